// Round 12
// baseline (327.772 us; speedup 1.0000x reference)
//
#include <hip/hip_runtime.h>
#include <hip/hip_bf16.h>
#include <math.h>

// Problem constants (fixed by the reference)
#define N_NODES 10000
#define N_EDGES 160000
#define BATCH   4096
#define DIM     512
#define HID     256

typedef short short8 __attribute__((ext_vector_type(8)));
typedef float f32x4  __attribute__((ext_vector_type(4)));

// ---------------------------------------------------------------------------
// graph build utilities
// ---------------------------------------------------------------------------
__global__ void zero_init_kernel(int* cnt, int* cursor, int* flag, int* pcnt,
                                 float* facc, int* fcnt) {
    int i = blockIdx.x * blockDim.x + threadIdx.x;
    if (i < N_NODES) { cnt[i] = 0; cursor[i] = 0; flag[i] = 0; }
    if (i == 0) { pcnt[0] = 0; facc[0] = 0.0f; fcnt[0] = 0; }
}

// degree count + label marking in one pass
__global__ void count_mark_kernel(const int* __restrict__ dst, const int* __restrict__ label,
                                  int* __restrict__ cnt, int* __restrict__ flag) {
    int e = blockIdx.x * blockDim.x + threadIdx.x;
    if (e < N_EDGES) atomicAdd(&cnt[dst[e]], 1);
    if (e < BATCH) flag[label[e]] = 1;          // idempotent, races benign
}

// block-local scan (256/block) + per-block sums; also computes dinv
__global__ __launch_bounds__(256) void scanA_kernel(const int* __restrict__ cnt,
        int* __restrict__ offs, int* __restrict__ bsum, float* __restrict__ dinv) {
    __shared__ int sh[256];
    int i = blockIdx.x * 256 + threadIdx.x;
    int v = (i < N_NODES) ? cnt[i] : 0;
    if (i < N_NODES) dinv[i] = rsqrtf((float)(1 + v));
    sh[threadIdx.x] = v;
    __syncthreads();
    for (int off = 1; off < 256; off <<= 1) {
        int t = (threadIdx.x >= (unsigned)off) ? sh[threadIdx.x - off] : 0;
        __syncthreads();
        sh[threadIdx.x] += t;
        __syncthreads();
    }
    if (i < N_NODES) offs[i] = sh[threadIdx.x] - v;   // exclusive within block
    if (threadIdx.x == 255) bsum[blockIdx.x] = sh[255];
}

// adds prefix of bsum (computed in-kernel; 40 entries)
__global__ __launch_bounds__(256) void scanC_kernel(int* __restrict__ offs,
                                                    const int* __restrict__ bsum) {
    int pre = 0;
    for (int b = 0; b < (int)blockIdx.x; ++b) pre += bsum[b];
    int i = blockIdx.x * 256 + threadIdx.x;
    if (i < N_NODES) offs[i] += pre;
    if (i == 0) offs[N_NODES] = N_EDGES;
}

// CSR fill (storing src id + dinv[src]) fused with label-set compaction
__global__ void fill_compact_kernel(const int* __restrict__ src, const int* __restrict__ dst,
                                    const int* __restrict__ offs, const float* __restrict__ dinv,
                                    int* __restrict__ cursor, int* __restrict__ csr_src,
                                    float* __restrict__ csr_w, const int* __restrict__ flag,
                                    int* __restrict__ pcnt, int* __restrict__ nodelist,
                                    int* __restrict__ pos) {
    int e = blockIdx.x * blockDim.x + threadIdx.x;
    if (e < N_EDGES) {
        int d = dst[e];
        int s = src[e];
        int p = offs[d] + atomicAdd(&cursor[d], 1);
        csr_src[p] = s;
        csr_w[p]   = dinv[s];
    }
    if (e < N_NODES && flag[e]) {
        int p = atomicAdd(pcnt, 1);
        nodelist[p] = e;
        pos[e] = p;
    }
}

// ---------------------------------------------------------------------------
// split-bf16 helpers
// ---------------------------------------------------------------------------
__device__ __forceinline__ unsigned short f2bf(float x) {
    unsigned u = __float_as_uint(x);
    return (unsigned short)((u + 0x7FFFu + ((u >> 16) & 1u)) >> 16);   // RNE
}
__device__ __forceinline__ float bf2f(unsigned short h) {
    return __uint_as_float(((unsigned)h) << 16);
}

// ---------------------------------------------------------------------------
// GCN aggregation body over 256 channels: wave-per-node, float4 per lane,
// 4 gathers in flight. EXTOUT: emit split-bf16 [hi|lo] row (2x256).
// ---------------------------------------------------------------------------
template <int BIAS, int RELU, int COMPACT, int EXTOUT>
__device__ __forceinline__ void agg_body(int wid_base, const float* __restrict__ xw,
        const float* __restrict__ dinv, const int* __restrict__ csr_src,
        const float* __restrict__ csr_w, const int* __restrict__ offs,
        const float* __restrict__ bias, void* __restrict__ out,
        const int* __restrict__ nodelist, const int* __restrict__ pcnt) {
    int wid  = wid_base + (threadIdx.x >> 6);
    int lane = threadIdx.x & 63;
    int n;
    if (COMPACT) { if (wid >= pcnt[0]) return; n = nodelist[wid]; }
    else         { if (wid >= N_NODES) return; n = wid; }
    int c4 = lane * 4;
    float di = dinv[n];
    float d2 = di * di;
    float4 self = *(const float4*)&xw[(size_t)n * 256 + c4];
    float4 a = make_float4(d2 * self.x, d2 * self.y, d2 * self.z, d2 * self.w);
    int s0 = offs[n], s1 = offs[n + 1];
    int i = s0;
    for (; i + 3 < s1; i += 4) {              // 4 gathers in flight
        int   sr0 = csr_src[i],     sr1 = csr_src[i + 1];
        int   sr2 = csr_src[i + 2], sr3 = csr_src[i + 3];
        float w0 = di * csr_w[i],     w1 = di * csr_w[i + 1];
        float w2 = di * csr_w[i + 2], w3 = di * csr_w[i + 3];
        float4 v0 = *(const float4*)&xw[(size_t)sr0 * 256 + c4];
        float4 v1 = *(const float4*)&xw[(size_t)sr1 * 256 + c4];
        float4 v2 = *(const float4*)&xw[(size_t)sr2 * 256 + c4];
        float4 v3 = *(const float4*)&xw[(size_t)sr3 * 256 + c4];
        a.x = fmaf(w0, v0.x, a.x); a.y = fmaf(w0, v0.y, a.y);
        a.z = fmaf(w0, v0.z, a.z); a.w = fmaf(w0, v0.w, a.w);
        a.x = fmaf(w1, v1.x, a.x); a.y = fmaf(w1, v1.y, a.y);
        a.z = fmaf(w1, v1.z, a.z); a.w = fmaf(w1, v1.w, a.w);
        a.x = fmaf(w2, v2.x, a.x); a.y = fmaf(w2, v2.y, a.y);
        a.z = fmaf(w2, v2.z, a.z); a.w = fmaf(w2, v2.w, a.w);
        a.x = fmaf(w3, v3.x, a.x); a.y = fmaf(w3, v3.y, a.y);
        a.z = fmaf(w3, v3.z, a.z); a.w = fmaf(w3, v3.w, a.w);
    }
    for (; i < s1; ++i) {
        int sr = csr_src[i];
        float wgt = di * csr_w[i];
        float4 v = *(const float4*)&xw[(size_t)sr * 256 + c4];
        a.x = fmaf(wgt, v.x, a.x); a.y = fmaf(wgt, v.y, a.y);
        a.z = fmaf(wgt, v.z, a.z); a.w = fmaf(wgt, v.w, a.w);
    }
    if (BIAS) {
        float4 b = *(const float4*)&bias[c4];
        a.x += b.x; a.y += b.y; a.z += b.z; a.w += b.w;
    }
    if (RELU) {
        a.x = fmaxf(a.x, 0.f); a.y = fmaxf(a.y, 0.f);
        a.z = fmaxf(a.z, 0.f); a.w = fmaxf(a.w, 0.f);
    }
    int orow = COMPACT ? wid : n;
    if (EXTOUT) {
        ushort4 h, l;
        h.x = f2bf(a.x); l.x = f2bf(a.x - bf2f(h.x));
        h.y = f2bf(a.y); l.y = f2bf(a.y - bf2f(h.y));
        h.z = f2bf(a.z); l.z = f2bf(a.z - bf2f(h.z));
        h.w = f2bf(a.w); l.w = f2bf(a.w - bf2f(h.w));
        unsigned short* ob = (unsigned short*)out + (size_t)orow * 512;
        *(ushort4*)&ob[c4]       = h;
        *(ushort4*)&ob[256 + c4] = l;
    } else {
        *(float4*)((float*)out + (size_t)orow * 256 + c4) = a;
    }
}

template <int BIAS, int RELU, int COMPACT, int EXTOUT>
__global__ __launch_bounds__(256) void agg256_kernel(const float* __restrict__ xw,
        const float* __restrict__ dinv, const int* __restrict__ csr_src,
        const float* __restrict__ csr_w, const int* __restrict__ offs,
        const float* __restrict__ bias, void* __restrict__ out,
        const int* __restrict__ nodelist, const int* __restrict__ pcnt) {
    agg_body<BIAS, RELU, COMPACT, EXTOUT>(blockIdx.x * 4, xw, dinv, csr_src, csr_w,
                                          offs, bias, out, nodelist, pcnt);
}

// ---------------------------------------------------------------------------
// ALL operand builds in one launch: row-ext for x_nodes + image, col-ext for
// the 4 weight matrices. Segmented flat grid.
// ---------------------------------------------------------------------------
__global__ __launch_bounds__(256) void build_all_kernel(
        const float* __restrict__ xn, const float* __restrict__ im,
        const float* __restrict__ Wg1, const float* __restrict__ Wi1,
        const float* __restrict__ Wg2, const float* __restrict__ Wi2,
        unsigned short* __restrict__ dxn, unsigned short* __restrict__ dim_,
        unsigned short* __restrict__ o1, unsigned short* __restrict__ o3,
        unsigned short* __restrict__ o2, unsigned short* __restrict__ o4) {
    int id = blockIdx.x * 256 + threadIdx.x;
    const int NA = (N_NODES + BATCH) * 128;        // row-ext domain
    if (id < NA) {
        const int NX = N_NODES * 128;
        int lid = (id < NX) ? id : id - NX;
        const float* src = (id < NX) ? xn : im;
        unsigned short* dst = (id < NX) ? dxn : dim_;
        int r  = lid >> 7;
        int c4 = (lid & 127) << 2;
        float4 v = *(const float4*)&src[(size_t)r * DIM + c4];
        ushort4 h, l;
        h.x = f2bf(v.x); l.x = f2bf(v.x - bf2f(h.x));
        h.y = f2bf(v.y); l.y = f2bf(v.y - bf2f(h.y));
        h.z = f2bf(v.z); l.z = f2bf(v.z - bf2f(h.z));
        h.w = f2bf(v.w); l.w = f2bf(v.w - bf2f(h.w));
        unsigned short* base = dst + (size_t)r * 1024;
        *(ushort4*)&base[c4]       = h;
        *(ushort4*)&base[512 + c4] = l;
    } else {
        int lid2 = id - NA;                        // [0, 131072)
        int seg  = lid2 >> 15;
        int lid  = lid2 & 32767;
        const float* src; unsigned short* dst; int K, N, kshift;
        if (seg == 0)      { src = Wg1; dst = o1; K = 512; N = 256; kshift = 7; }
        else if (seg == 1) { src = Wi1; dst = o3; K = 512; N = 256; kshift = 7; }
        else if (seg == 2) { src = Wg2; dst = o2; K = 256; N = 512; kshift = 6; }
        else               { src = Wi2; dst = o4; K = 256; N = 512; kshift = 6; }
        int n  = lid >> kshift;
        int c4 = (lid & ((1 << kshift) - 1)) << 2;
        float v0 = src[(size_t)(c4 + 0) * N + n];
        float v1 = src[(size_t)(c4 + 1) * N + n];
        float v2 = src[(size_t)(c4 + 2) * N + n];
        float v3 = src[(size_t)(c4 + 3) * N + n];
        ushort4 h, l;
        h.x = f2bf(v0); l.x = f2bf(v0 - bf2f(h.x));
        h.y = f2bf(v1); l.y = f2bf(v1 - bf2f(h.y));
        h.z = f2bf(v2); l.z = f2bf(v2 - bf2f(h.z));
        h.w = f2bf(v3); l.w = f2bf(v3 - bf2f(h.w));
        unsigned short* base = dst + (size_t)n * 2 * K;
        *(ushort4*)&base[c4]     = h;
        *(ushort4*)&base[K + c4] = l;
    }
}

// ---------------------------------------------------------------------------
__device__ __forceinline__ void gld_lds16(const void* g, void* l) {
    __builtin_amdgcn_global_load_lds(
        (const __attribute__((address_space(1))) unsigned int*)g,
        (__attribute__((address_space(3))) unsigned int*)l, 16, 0, 0);
}

// ---------------------------------------------------------------------------
// Dense MFMA GEMM body on [hi|lo] ext operands: C = A.B^T, 3-product split-bf16.
// tile 128x64, 4 waves (2x2), wave = 64x32. Runtime bias/relu/ext flags are
// block-uniform (scalar branches). sh = 12288 ushorts (A 16KB + B 8KB).
// ---------------------------------------------------------------------------
__device__ __forceinline__ void gemm_body(
        const unsigned short* __restrict__ Aext, const unsigned short* __restrict__ Bext,
        const float* __restrict__ bias, void* __restrict__ Cout,
        int M, int N, int K, int rt, int ct, int relu, int ext,
        unsigned short* sh) {
    if (rt * 128 >= M) return;               // uniform early-exit (dead row tile)
    int t    = threadIdx.x;
    int lane = t & 63;
    int w    = t >> 6;
    int wy   = w >> 1, wx = w & 1;
    int m    = lane & 15;
    int q    = lane >> 4;

    int ra0 = rt * 128 + w * 16 + m;        if (ra0 > M - 1) ra0 = M - 1;
    int ra1 = rt * 128 + (4 + w) * 16 + m;  if (ra1 > M - 1) ra1 = M - 1;
    int rb  = ct * 64 + w * 16 + m;
    const unsigned short* pa0 = Aext + (size_t)ra0 * 2 * K + q * 8;
    const unsigned short* pa1 = Aext + (size_t)ra1 * 2 * K + q * 8;
    const unsigned short* pb  = Bext + (size_t)rb  * 2 * K + q * 8;
    unsigned short* Bs = sh + 8192;

    f32x4 acc[4][2];
#pragma unroll
    for (int i = 0; i < 4; ++i)
#pragma unroll
        for (int j = 0; j < 2; ++j) acc[i][j] = (f32x4){0.f, 0.f, 0.f, 0.f};

    for (int k0 = 0; k0 < K; k0 += 32) {
        gld_lds16(pa0 + k0,     sh + (w * 2 + 0) * 512);
        gld_lds16(pa0 + K + k0, sh + (w * 2 + 1) * 512);
        gld_lds16(pa1 + k0,     sh + ((4 + w) * 2 + 0) * 512);
        gld_lds16(pa1 + K + k0, sh + ((4 + w) * 2 + 1) * 512);
        gld_lds16(pb + k0,      Bs + (w * 2 + 0) * 512);
        gld_lds16(pb + K + k0,  Bs + (w * 2 + 1) * 512);
        __syncthreads();
        short8 ah[4], al[4];
#pragma unroll
        for (int i = 0; i < 4; ++i) {
            ah[i] = *(const short8*)&sh[((wy * 4 + i) * 2 + 0) * 512 + lane * 8];
            al[i] = *(const short8*)&sh[((wy * 4 + i) * 2 + 1) * 512 + lane * 8];
        }
#pragma unroll
        for (int j = 0; j < 2; ++j) {
            short8 bh = *(const short8*)&Bs[((wx * 2 + j) * 2 + 0) * 512 + lane * 8];
            short8 bl = *(const short8*)&Bs[((wx * 2 + j) * 2 + 1) * 512 + lane * 8];
#pragma unroll
            for (int i = 0; i < 4; ++i) {
                acc[i][j] = __builtin_amdgcn_mfma_f32_16x16x32_bf16(ah[i], bh, acc[i][j], 0, 0, 0);
                acc[i][j] = __builtin_amdgcn_mfma_f32_16x16x32_bf16(al[i], bh, acc[i][j], 0, 0, 0);
                acc[i][j] = __builtin_amdgcn_mfma_f32_16x16x32_bf16(ah[i], bl, acc[i][j], 0, 0, 0);
            }
        }
        __syncthreads();
    }

    float b0 = 0.f, b1 = 0.f;
    if (bias) {
        b0 = bias[ct * 64 + wx * 32 + m];
        b1 = bias[ct * 64 + wx * 32 + 16 + m];
    }
#pragma unroll
    for (int i = 0; i < 4; ++i) {
        int rbase = rt * 128 + wy * 64 + i * 16 + q * 4;
#pragma unroll
        for (int j = 0; j < 2; ++j) {
            int col = ct * 64 + wx * 32 + j * 16 + m;
            float bb = j ? b1 : b0;
#pragma unroll
            for (int reg = 0; reg < 4; ++reg) {
                int row = rbase + reg;
                if (row < M) {
                    float v = acc[i][j][reg] + bb;
                    if (relu) v = fmaxf(v, 0.f);
                    if (ext == 0) {
                        ((float*)Cout)[(size_t)row * N + col] = v;
                    } else {
                        unsigned short hi = f2bf(v);
                        unsigned short lo = f2bf(v - bf2f(hi));
                        unsigned short* ob = (unsigned short*)Cout + (size_t)row * 2 * N;
                        ob[col] = hi; ob[N + col] = lo;
                    }
                }
            }
        }
    }
}

// dualA: GCN1 GEMM (ct 0..3, rt 0..78, M=10000, fp32 out) + MLP1 (ct 4..7,
// rt 0..31, M=4096, relu+ext out). Independent — share one launch.
__global__ __launch_bounds__(256, 4) void mfma_gemm_dualA_kernel(
        const unsigned short* __restrict__ A0, const unsigned short* __restrict__ B0,
        void* __restrict__ C0,
        const unsigned short* __restrict__ A1, const unsigned short* __restrict__ B1,
        const float* __restrict__ bias1, void* __restrict__ C1) {
    __shared__ __align__(16) unsigned short sh[12288];
    if ((int)blockIdx.x < 4) {
        gemm_body(A0, B0, nullptr, C0, N_NODES, HID, DIM, blockIdx.y, blockIdx.x, 0, 0, sh);
    } else {
        gemm_body(A1, B1, bias1, C1, BATCH, HID, DIM, blockIdx.y, blockIdx.x - 4, 1, 1, sh);
    }
}

// fused: GCN1 aggregation (blocks [0, 2500)) + MLP2 GEMM (blocks [2500, 2756))
// — both depend only on dualA's outputs; MLP2 rides in agg1's shadow.
__global__ __launch_bounds__(256, 4) void agg_mlp2_kernel(
        const float* __restrict__ xw1, const float* __restrict__ dinv,
        const int* __restrict__ csr_src, const float* __restrict__ csr_w,
        const int* __restrict__ offs, const float* __restrict__ b_g1,
        float* __restrict__ h,
        const unsigned short* __restrict__ A1, const unsigned short* __restrict__ B1,
        const float* __restrict__ bias1, void* __restrict__ C1) {
    __shared__ __align__(16) unsigned short sh[12288];
    if ((int)blockIdx.x < 2500) {
        agg_body<1, 1, 0, 0>(blockIdx.x * 4, xw1, dinv, csr_src, csr_w, offs,
                             b_g1, h, nullptr, nullptr);
    } else {
        int bid = blockIdx.x - 2500;          // 0..255
        gemm_body(A1, B1, bias1, C1, BATCH, DIM, HID, bid >> 3, bid & 7, 1, 1, sh);
    }
}

// GCN2 GEMM alone (M = pcnt device-side, ext out); dead rt blocks early-exit.
__global__ __launch_bounds__(256, 4) void mfma_gemm_g2_kernel(
        const unsigned short* __restrict__ A0, const unsigned short* __restrict__ B0,
        const float* __restrict__ bias0, void* __restrict__ C0,
        const int* __restrict__ Mptr0) {
    __shared__ __align__(16) unsigned short sh[12288];
    gemm_body(A0, B0, bias0, C0, Mptr0[0], DIM, HID, blockIdx.y, blockIdx.x, 0, 1, sh);
}

// ---------------------------------------------------------------------------
// logits = A @ B^T on [hi|lo] ext (K=512, 3-product split-bf16) + fused online
// softmax partials. 256x128 tile, 512 thr = 8 waves (4x2), wave = 64x64.
// 48 KB LDS -> 2 blocks/CU; 512 blocks full residency. In-kernel A-gather via
// pos[label]; fragment-order LDS (conflict-free); XCD swizzle.
// ---------------------------------------------------------------------------
__global__ __launch_bounds__(512, 4) void logits_mfma_kernel(
        const unsigned short* __restrict__ Aext, const unsigned short* __restrict__ Bext,
        const int* __restrict__ label, const int* __restrict__ pos,
        float* __restrict__ pmax, float* __restrict__ psum, float* __restrict__ diagv) {
    __shared__ __align__(16) unsigned short sh[24576];   // 48 KB: A 32KB (16 chunks) + B 16KB (8)
    unsigned short* Bs = sh + 16384;

    int t    = threadIdx.x;
    int lane = t & 63;
    int w    = t >> 6;            // wave 0..7
    int wy   = w >> 1, wx = w & 1;
    // XCD swizzle over 512 blocks = 16 rt x 32 ct; per-XCD region 8rt x 8ct
    int g   = blockIdx.x;
    int xcd = g & 7, s = g >> 3;              // s in 0..63
    int rt  = (xcd & 1) * 8 + (s & 7);        // 0..15 (256-row tiles)
    int ct  = (xcd >> 1) * 8 + (s >> 3);      // 0..31 (128-col tiles)
    int m    = lane & 15;
    int q    = lane >> 4;

    // staging: wave w owns A chunks (w*2, w*2+1) and B chunk w (16 rows each)
    int ar0 = pos[label[rt * 256 + (w * 2 + 0) * 16 + m]];
    int ar1 = pos[label[rt * 256 + (w * 2 + 1) * 16 + m]];
    const unsigned short* ap0 = Aext + (size_t)ar0 * 1024 + q * 8;
    const unsigned short* ap1 = Aext + (size_t)ar1 * 1024 + q * 8;
    const unsigned short* bp  = Bext + (size_t)(ct * 128 + w * 16 + m) * 1024 + q * 8;

    f32x4 acc[4][4];
#pragma unroll
    for (int i = 0; i < 4; ++i)
#pragma unroll
        for (int j = 0; j < 4; ++j) acc[i][j] = (f32x4){0.f, 0.f, 0.f, 0.f};

    for (int k0 = 0; k0 < 512; k0 += 32) {
        gld_lds16(ap0 + k0,       sh + ((w * 2 + 0) * 2 + 0) * 512);
        gld_lds16(ap0 + 512 + k0, sh + ((w * 2 + 0) * 2 + 1) * 512);
        gld_lds16(ap1 + k0,       sh + ((w * 2 + 1) * 2 + 0) * 512);
        gld_lds16(ap1 + 512 + k0, sh + ((w * 2 + 1) * 2 + 1) * 512);
        gld_lds16(bp + k0,        Bs + (w * 2 + 0) * 512);
        gld_lds16(bp + 512 + k0,  Bs + (w * 2 + 1) * 512);
        __syncthreads();                 // drains vmcnt: staging complete
        short8 ah[4], al[4];
#pragma unroll
        for (int i = 0; i < 4; ++i) {
            ah[i] = *(const short8*)&sh[((wy * 4 + i) * 2 + 0) * 512 + lane * 8];
            al[i] = *(const short8*)&sh[((wy * 4 + i) * 2 + 1) * 512 + lane * 8];
        }
#pragma unroll
        for (int j = 0; j < 4; ++j) {
            short8 bh = *(const short8*)&Bs[((wx * 4 + j) * 2 + 0) * 512 + lane * 8];
            short8 bl = *(const short8*)&Bs[((wx * 4 + j) * 2 + 1) * 512 + lane * 8];
#pragma unroll
            for (int i = 0; i < 4; ++i) {
                acc[i][j] = __builtin_amdgcn_mfma_f32_16x16x32_bf16(ah[i], bh, acc[i][j], 0, 0, 0);
                acc[i][j] = __builtin_amdgcn_mfma_f32_16x16x32_bf16(al[i], bh, acc[i][j], 0, 0, 0);
                acc[i][j] = __builtin_amdgcn_mfma_f32_16x16x32_bf16(ah[i], bl, acc[i][j], 0, 0, 0);
            }
        }
        __syncthreads();                 // WAR before next staging
    }

    // C/D layout: col = lane&15, row = q*4 + reg (within each 16x16 tile)
    // diagonal: block touches it iff ct>>1 == rt
    if ((ct >> 1) == rt) {
#pragma unroll
        for (int i = 0; i < 4; ++i)
#pragma unroll
            for (int j = 0; j < 4; ++j)
#pragma unroll
                for (int reg = 0; reg < 4; ++reg) {
                    int row = rt * 256 + wy * 64 + i * 16 + q * 4 + reg;
                    int col = ct * 128 + wx * 64 + j * 16 + m;
                    if (row == col) diagv[row] = acc[i][j][reg];
                }
    }

    // per-row (max, sumexp) over this wave's 64 cols
#pragma unroll
    for (int mt = 0; mt < 4; ++mt) {
#pragma unroll
        for (int reg = 0; reg < 4; ++reg) {
            float v0 = acc[mt][0][reg], v1 = acc[mt][1][reg];
            float v2 = acc[mt][2][reg], v3 = acc[mt][3][reg];
            float mx = fmaxf(fmaxf(v0, v1), fmaxf(v2, v3));
#pragma unroll
            for (int d = 1; d < 16; d <<= 1) mx = fmaxf(mx, __shfl_xor(mx, d, 64));
            float sm = __expf(v0 - mx) + __expf(v1 - mx) + __expf(v2 - mx) + __expf(v3 - mx);
#pragma unroll
            for (int d = 1; d < 16; d <<= 1) sm += __shfl_xor(sm, d, 64);
            if (m == 0) {
                int row = rt * 256 + wy * 64 + mt * 16 + q * 4 + reg;
                pmax[(size_t)row * 64 + ct * 2 + wx] = mx;
                psum[(size_t)row * 64 + ct * 2 + wx] = sm;
            }
        }
    }
}

// combine 64 col-tile partials per row -> per-row loss term; fused final
// reduction via device-scope atomics (last block writes out[0]).
__global__ __launch_bounds__(256) void row_finalize_kernel(const float* __restrict__ pmax,
        const float* __restrict__ psum, const float* __restrict__ diagv,
        const int* __restrict__ label, float* __restrict__ facc, int* __restrict__ fcnt,
        float* __restrict__ out) {
    __shared__ float wsum[4];
    int gid  = blockIdx.x * blockDim.x + threadIdx.x;
    int row  = gid >> 6;
    int lane = threadIdx.x & 63;
    int wv   = threadIdx.x >> 6;
    float term = 0.0f;
    if (row < BATCH) {
        float m = pmax[(size_t)row * 64 + lane];
        float s = psum[(size_t)row * 64 + lane];
        float M = m;
#pragma unroll
        for (int d = 1; d < 64; d <<= 1) M = fmaxf(M, __shfl_xor(M, d, 64));
        s *= __expf(m - M);
#pragma unroll
        for (int d = 1; d < 64; d <<= 1) s += __shfl_xor(s, d, 64);
        float lse = M + __logf(s);
        term = -(float)label[row] * (diagv[row] - lse);
    }
    if (lane == 0) wsum[wv] = (row < BATCH) ? term : 0.0f;
    __syncthreads();
    if (threadIdx.x == 0) {
        float p = wsum[0] + wsum[1] + wsum[2] + wsum[3];
        atomicAdd(facc, p);
        __threadfence();
        int old = atomicAdd(fcnt, 1);
        if (old == (int)gridDim.x - 1) {
            float tot = atomicAdd(facc, 0.0f);   // device-scope coherent read
            // contrastive mean + triplet loss (identically 1.0: d_ap==d_an)
            out[0] = tot / (float)BATCH + 1.0f;
        }
    }
}

// ---------------------------------------------------------------------------
extern "C" void kernel_launch(void* const* d_in, const int* in_sizes, int n_in,
                              void* d_out, int out_size, void* d_ws, size_t ws_size,
                              hipStream_t stream) {
    const float* image   = (const float*)d_in[0];
    const float* x_nodes = (const float*)d_in[1];
    const int*   edge    = (const int*)d_in[2];
    const int*   label   = (const int*)d_in[3];
    const float* W_img1  = (const float*)d_in[4];
    const float* b_img1  = (const float*)d_in[5];
    const float* W_img2  = (const float*)d_in[6];
    const float* b_img2  = (const float*)d_in[7];
    const float* W_g1    = (const float*)d_in[8];
    const float* b_g1    = (const float*)d_in[9];
    const float* W_g2    = (const float*)d_in[10];
    const float* b_g2    = (const float*)d_in[11];
    const int* src = edge;              // edge_index[0]
    const int* dst = edge + N_EDGES;    // edge_index[1]

    // workspace carve-up (256B aligned regions)
    char* ws = (char*)d_ws;
    size_t off = 0;
    auto alloc = [&](size_t bytes) { size_t r = off; off = (off + bytes + 255) & ~(size_t)255; return r; };
    float* dinv     = (float*)(ws + alloc(N_NODES * 4));
    int*   cnt      = (int*)  (ws + alloc(N_NODES * 4));
    int*   offs     = (int*)  (ws + alloc((N_NODES + 1) * 4));
    int*   cursor   = (int*)  (ws + alloc(N_NODES * 4));
    int*   csr_src  = (int*)  (ws + alloc(N_EDGES * 4));
    float* csr_w    = (float*)(ws + alloc(N_EDGES * 4));
    int*   flag     = (int*)  (ws + alloc(N_NODES * 4));
    int*   pos      = (int*)  (ws + alloc(N_NODES * 4));
    int*   nodelist = (int*)  (ws + alloc(BATCH * 4));
    int*   pcnt     = (int*)  (ws + alloc(4));
    int*   bsum     = (int*)  (ws + alloc(64 * 4));
    float* facc     = (float*)(ws + alloc(4));
    int*   fcnt     = (int*)  (ws + alloc(4));
    float* xw1      = (float*)(ws + alloc((size_t)N_NODES * HID * 4));
    float* h        = (float*)(ws + alloc((size_t)N_NODES * HID * 4));
    unsigned short* g2inext = (unsigned short*)(ws + alloc((size_t)BATCH * 2 * HID * 2));
    unsigned short* g2ext   = (unsigned short*)(ws + alloc((size_t)BATCH * 2 * DIM * 2));
    unsigned short* himgext = (unsigned short*)(ws + alloc((size_t)BATCH * 2 * HID * 2));
    unsigned short* extbuf  = (unsigned short*)(ws + alloc((size_t)N_NODES * 2 * DIM * 2));
    unsigned short* imgext  = (unsigned short*)(ws + alloc((size_t)BATCH * 2 * DIM * 2));
    unsigned short* wext1   = (unsigned short*)(ws + alloc((size_t)HID * 2 * DIM * 2));
    unsigned short* wext2   = (unsigned short*)(ws + alloc((size_t)DIM * 2 * HID * 2));
    unsigned short* wext3   = (unsigned short*)(ws + alloc((size_t)HID * 2 * DIM * 2));
    unsigned short* wext4   = (unsigned short*)(ws + alloc((size_t)DIM * 2 * HID * 2));
    unsigned short* Bext    = (unsigned short*)(ws + alloc((size_t)BATCH * 2 * DIM * 2));
    float* pmax  = (float*)(ws + alloc((size_t)BATCH * 64 * 4));
    float* psum  = (float*)(ws + alloc((size_t)BATCH * 64 * 4));
    float* diagv = (float*)(ws + alloc(BATCH * 4));

    const int SCAN_BLOCKS = (N_NODES + 255) / 256;   // 40

    // graph build: CSR by dst (storing src+weight) + dinv + label compaction
    zero_init_kernel<<<SCAN_BLOCKS, 256, 0, stream>>>(cnt, cursor, flag, pcnt, facc, fcnt);
    count_mark_kernel<<<(N_EDGES + 255) / 256, 256, 0, stream>>>(dst, label, cnt, flag);
    scanA_kernel<<<SCAN_BLOCKS, 256, 0, stream>>>(cnt, offs, bsum, dinv);
    scanC_kernel<<<SCAN_BLOCKS, 256, 0, stream>>>(offs, bsum);
    fill_compact_kernel<<<(N_EDGES + 255) / 256, 256, 0, stream>>>(
        src, dst, offs, dinv, cursor, csr_src, csr_w, flag, pcnt, nodelist, pos);

    // all operand builds (x_nodes + image row-ext, 4 weight col-ext) in one launch
    build_all_kernel<<<((N_NODES + BATCH) * 128 + 4 * 32768) / 256, 256, 0, stream>>>(
        x_nodes, image, W_g1, W_img1, W_g2, W_img2,
        extbuf, imgext, wext1, wext3, wext2, wext4);

    // dualA: GCN1 GEMM (xw1 = x_nodes @ W_g1) + MLP1 (himgext) — independent
    mfma_gemm_dualA_kernel<<<dim3(8, (N_NODES + 127) / 128), 256, 0, stream>>>(
        extbuf, wext1, xw1, imgext, wext3, b_img1, himgext);

    // fused: GCN1 aggregation (h = relu(A-hat xw1 + b1)) + MLP2 (Bext)
    agg_mlp2_kernel<<<2500 + 256, 256, 0, stream>>>(
        xw1, dinv, csr_src, csr_w, offs, b_g1, h,
        himgext, wext4, b_img2, Bext);

    // GCN layer 2 aggregation (compact label rows)
    agg256_kernel<0, 0, 1, 1><<<BATCH / 4, 256, 0, stream>>>(
        h, dinv, csr_src, csr_w, offs, nullptr, g2inext, nodelist, pcnt);

    // GCN2 GEMM (g2ext, M = pcnt device-side)
    mfma_gemm_g2_kernel<<<dim3(8, BATCH / 128), 256, 0, stream>>>(
        g2inext, wext2, b_g2, g2ext, pcnt);

    // fused logits (split-bf16 MFMA, 256x128 tile) + online softmax partials
    logits_mfma_kernel<<<512, 512, 0, stream>>>(g2ext, Bext, label, pos,
                                                pmax, psum, diagv);
    // per-row LSE + fused mean + triplet constant
    row_finalize_kernel<<<(BATCH * 64) / 256, 256, 0, stream>>>(
        pmax, psum, diagv, label, facc, fcnt, (float*)d_out);
}

// Round 13
// 314.305 us; speedup vs baseline: 1.0428x; 1.0428x over previous
//
#include <hip/hip_runtime.h>
#include <hip/hip_bf16.h>
#include <math.h>

// Problem constants (fixed by the reference)
#define N_NODES 10000
#define N_EDGES 160000
#define BATCH   4096
#define DIM     512
#define HID     256

typedef short short8 __attribute__((ext_vector_type(8)));
typedef float f32x4  __attribute__((ext_vector_type(4)));

// ---------------------------------------------------------------------------
// graph build utilities
// ---------------------------------------------------------------------------
__global__ void zero_init_kernel(int* cnt, int* cursor, int* flag, int* pcnt,
                                 float* facc, int* fcnt) {
    int i = blockIdx.x * blockDim.x + threadIdx.x;
    if (i < N_NODES) { cnt[i] = 0; cursor[i] = 0; flag[i] = 0; }
    if (i == 0) { pcnt[0] = 0; facc[0] = 0.0f; fcnt[0] = 0; }
}

// degree count + label marking in one pass
__global__ void count_mark_kernel(const int* __restrict__ dst, const int* __restrict__ label,
                                  int* __restrict__ cnt, int* __restrict__ flag) {
    int e = blockIdx.x * blockDim.x + threadIdx.x;
    if (e < N_EDGES) atomicAdd(&cnt[dst[e]], 1);
    if (e < BATCH) flag[label[e]] = 1;          // idempotent, races benign
}

// block-local scan (256/block) + per-block sums; also computes dinv
__global__ __launch_bounds__(256) void scanA_kernel(const int* __restrict__ cnt,
        int* __restrict__ offs, int* __restrict__ bsum, float* __restrict__ dinv) {
    __shared__ int sh[256];
    int i = blockIdx.x * 256 + threadIdx.x;
    int v = (i < N_NODES) ? cnt[i] : 0;
    if (i < N_NODES) dinv[i] = rsqrtf((float)(1 + v));
    sh[threadIdx.x] = v;
    __syncthreads();
    for (int off = 1; off < 256; off <<= 1) {
        int t = (threadIdx.x >= (unsigned)off) ? sh[threadIdx.x - off] : 0;
        __syncthreads();
        sh[threadIdx.x] += t;
        __syncthreads();
    }
    if (i < N_NODES) offs[i] = sh[threadIdx.x] - v;   // exclusive within block
    if (threadIdx.x == 255) bsum[blockIdx.x] = sh[255];
}

// adds prefix of bsum (computed in-kernel; 40 entries)
__global__ __launch_bounds__(256) void scanC_kernel(int* __restrict__ offs,
                                                    const int* __restrict__ bsum) {
    int pre = 0;
    for (int b = 0; b < (int)blockIdx.x; ++b) pre += bsum[b];
    int i = blockIdx.x * 256 + threadIdx.x;
    if (i < N_NODES) offs[i] += pre;
    if (i == 0) offs[N_NODES] = N_EDGES;
}

// CSR fill (storing src id + dinv[src]) fused with label-set compaction
__global__ void fill_compact_kernel(const int* __restrict__ src, const int* __restrict__ dst,
                                    const int* __restrict__ offs, const float* __restrict__ dinv,
                                    int* __restrict__ cursor, int* __restrict__ csr_src,
                                    float* __restrict__ csr_w, const int* __restrict__ flag,
                                    int* __restrict__ pcnt, int* __restrict__ nodelist,
                                    int* __restrict__ pos) {
    int e = blockIdx.x * blockDim.x + threadIdx.x;
    if (e < N_EDGES) {
        int d = dst[e];
        int s = src[e];
        int p = offs[d] + atomicAdd(&cursor[d], 1);
        csr_src[p] = s;
        csr_w[p]   = dinv[s];
    }
    if (e < N_NODES && flag[e]) {
        int p = atomicAdd(pcnt, 1);
        nodelist[p] = e;
        pos[e] = p;
    }
}

// ---------------------------------------------------------------------------
// split-bf16 helpers
// ---------------------------------------------------------------------------
__device__ __forceinline__ unsigned short f2bf(float x) {
    unsigned u = __float_as_uint(x);
    return (unsigned short)((u + 0x7FFFu + ((u >> 16) & 1u)) >> 16);   // RNE
}
__device__ __forceinline__ float bf2f(unsigned short h) {
    return __uint_as_float(((unsigned)h) << 16);
}

// ---------------------------------------------------------------------------
// GCN aggregation over 256 channels: wave-per-node, float4 per lane,
// 4 gathers in flight. EXTOUT: emit split-bf16 [hi|lo] row (2x256).
// NOTE: no LDS — keep it that way (occupancy-bound gather; R12's fusion with
// an LDS kernel cut agg occupancy and regressed 11 us).
// ---------------------------------------------------------------------------
template <int BIAS, int RELU, int COMPACT, int EXTOUT>
__global__ __launch_bounds__(256) void agg256_kernel(const float* __restrict__ xw,
        const float* __restrict__ dinv, const int* __restrict__ csr_src,
        const float* __restrict__ csr_w, const int* __restrict__ offs,
        const float* __restrict__ bias, void* __restrict__ out,
        const int* __restrict__ nodelist, const int* __restrict__ pcnt) {
    int wid  = blockIdx.x * 4 + (threadIdx.x >> 6);
    int lane = threadIdx.x & 63;
    int n;
    if (COMPACT) { if (wid >= pcnt[0]) return; n = nodelist[wid]; }
    else         { if (wid >= N_NODES) return; n = wid; }
    int c4 = lane * 4;
    float di = dinv[n];
    float d2 = di * di;
    float4 self = *(const float4*)&xw[(size_t)n * 256 + c4];
    float4 a = make_float4(d2 * self.x, d2 * self.y, d2 * self.z, d2 * self.w);
    int s0 = offs[n], s1 = offs[n + 1];
    int i = s0;
    for (; i + 3 < s1; i += 4) {              // 4 gathers in flight
        int   sr0 = csr_src[i],     sr1 = csr_src[i + 1];
        int   sr2 = csr_src[i + 2], sr3 = csr_src[i + 3];
        float w0 = di * csr_w[i],     w1 = di * csr_w[i + 1];
        float w2 = di * csr_w[i + 2], w3 = di * csr_w[i + 3];
        float4 v0 = *(const float4*)&xw[(size_t)sr0 * 256 + c4];
        float4 v1 = *(const float4*)&xw[(size_t)sr1 * 256 + c4];
        float4 v2 = *(const float4*)&xw[(size_t)sr2 * 256 + c4];
        float4 v3 = *(const float4*)&xw[(size_t)sr3 * 256 + c4];
        a.x = fmaf(w0, v0.x, a.x); a.y = fmaf(w0, v0.y, a.y);
        a.z = fmaf(w0, v0.z, a.z); a.w = fmaf(w0, v0.w, a.w);
        a.x = fmaf(w1, v1.x, a.x); a.y = fmaf(w1, v1.y, a.y);
        a.z = fmaf(w1, v1.z, a.z); a.w = fmaf(w1, v1.w, a.w);
        a.x = fmaf(w2, v2.x, a.x); a.y = fmaf(w2, v2.y, a.y);
        a.z = fmaf(w2, v2.z, a.z); a.w = fmaf(w2, v2.w, a.w);
        a.x = fmaf(w3, v3.x, a.x); a.y = fmaf(w3, v3.y, a.y);
        a.z = fmaf(w3, v3.z, a.z); a.w = fmaf(w3, v3.w, a.w);
    }
    for (; i < s1; ++i) {
        int sr = csr_src[i];
        float wgt = di * csr_w[i];
        float4 v = *(const float4*)&xw[(size_t)sr * 256 + c4];
        a.x = fmaf(wgt, v.x, a.x); a.y = fmaf(wgt, v.y, a.y);
        a.z = fmaf(wgt, v.z, a.z); a.w = fmaf(wgt, v.w, a.w);
    }
    if (BIAS) {
        float4 b = *(const float4*)&bias[c4];
        a.x += b.x; a.y += b.y; a.z += b.z; a.w += b.w;
    }
    if (RELU) {
        a.x = fmaxf(a.x, 0.f); a.y = fmaxf(a.y, 0.f);
        a.z = fmaxf(a.z, 0.f); a.w = fmaxf(a.w, 0.f);
    }
    int orow = COMPACT ? wid : n;
    if (EXTOUT) {
        ushort4 h, l;
        h.x = f2bf(a.x); l.x = f2bf(a.x - bf2f(h.x));
        h.y = f2bf(a.y); l.y = f2bf(a.y - bf2f(h.y));
        h.z = f2bf(a.z); l.z = f2bf(a.z - bf2f(h.z));
        h.w = f2bf(a.w); l.w = f2bf(a.w - bf2f(h.w));
        unsigned short* ob = (unsigned short*)out + (size_t)orow * 512;
        *(ushort4*)&ob[c4]       = h;
        *(ushort4*)&ob[256 + c4] = l;
    } else {
        *(float4*)((float*)out + (size_t)orow * 256 + c4) = a;
    }
}

// ---------------------------------------------------------------------------
// ALL operand builds in one launch: row-ext for x_nodes + image, col-ext for
// the 4 weight matrices. Segmented flat grid.
// ---------------------------------------------------------------------------
__global__ __launch_bounds__(256) void build_all_kernel(
        const float* __restrict__ xn, const float* __restrict__ im,
        const float* __restrict__ Wg1, const float* __restrict__ Wi1,
        const float* __restrict__ Wg2, const float* __restrict__ Wi2,
        unsigned short* __restrict__ dxn, unsigned short* __restrict__ dim_,
        unsigned short* __restrict__ o1, unsigned short* __restrict__ o3,
        unsigned short* __restrict__ o2, unsigned short* __restrict__ o4) {
    int id = blockIdx.x * 256 + threadIdx.x;
    const int NA = (N_NODES + BATCH) * 128;        // row-ext domain
    if (id < NA) {
        const int NX = N_NODES * 128;
        int lid = (id < NX) ? id : id - NX;
        const float* src = (id < NX) ? xn : im;
        unsigned short* dst = (id < NX) ? dxn : dim_;
        int r  = lid >> 7;
        int c4 = (lid & 127) << 2;
        float4 v = *(const float4*)&src[(size_t)r * DIM + c4];
        ushort4 h, l;
        h.x = f2bf(v.x); l.x = f2bf(v.x - bf2f(h.x));
        h.y = f2bf(v.y); l.y = f2bf(v.y - bf2f(h.y));
        h.z = f2bf(v.z); l.z = f2bf(v.z - bf2f(h.z));
        h.w = f2bf(v.w); l.w = f2bf(v.w - bf2f(h.w));
        unsigned short* base = dst + (size_t)r * 1024;
        *(ushort4*)&base[c4]       = h;
        *(ushort4*)&base[512 + c4] = l;
    } else {
        int lid2 = id - NA;                        // [0, 131072)
        int seg  = lid2 >> 15;
        int lid  = lid2 & 32767;
        const float* src; unsigned short* dst; int K, N, kshift;
        if (seg == 0)      { src = Wg1; dst = o1; K = 512; N = 256; kshift = 7; }
        else if (seg == 1) { src = Wi1; dst = o3; K = 512; N = 256; kshift = 7; }
        else if (seg == 2) { src = Wg2; dst = o2; K = 256; N = 512; kshift = 6; }
        else               { src = Wi2; dst = o4; K = 256; N = 512; kshift = 6; }
        int n  = lid >> kshift;
        int c4 = (lid & ((1 << kshift) - 1)) << 2;
        float v0 = src[(size_t)(c4 + 0) * N + n];
        float v1 = src[(size_t)(c4 + 1) * N + n];
        float v2 = src[(size_t)(c4 + 2) * N + n];
        float v3 = src[(size_t)(c4 + 3) * N + n];
        ushort4 h, l;
        h.x = f2bf(v0); l.x = f2bf(v0 - bf2f(h.x));
        h.y = f2bf(v1); l.y = f2bf(v1 - bf2f(h.y));
        h.z = f2bf(v2); l.z = f2bf(v2 - bf2f(h.z));
        h.w = f2bf(v3); l.w = f2bf(v3 - bf2f(h.w));
        unsigned short* base = dst + (size_t)n * 2 * K;
        *(ushort4*)&base[c4]     = h;
        *(ushort4*)&base[K + c4] = l;
    }
}

// ---------------------------------------------------------------------------
__device__ __forceinline__ void gld_lds16(const void* g, void* l) {
    __builtin_amdgcn_global_load_lds(
        (const __attribute__((address_space(1))) unsigned int*)g,
        (__attribute__((address_space(3))) unsigned int*)l, 16, 0, 0);
}

// ---------------------------------------------------------------------------
// Dense MFMA GEMM body on [hi|lo] ext operands: C = A.B^T, 3-product split-bf16.
// tile 128x64, 4 waves (2x2), wave = 64x32. Runtime bias/relu/ext flags are
// block-uniform (scalar branches). sh = 12288 ushorts (A 16KB + B 8KB).
// ---------------------------------------------------------------------------
__device__ __forceinline__ void gemm_body(
        const unsigned short* __restrict__ Aext, const unsigned short* __restrict__ Bext,
        const float* __restrict__ bias, void* __restrict__ Cout,
        int M, int N, int K, int rt, int ct, int relu, int ext,
        unsigned short* sh) {
    if (rt * 128 >= M) return;               // uniform early-exit (dead row tile)
    int t    = threadIdx.x;
    int lane = t & 63;
    int w    = t >> 6;
    int wy   = w >> 1, wx = w & 1;
    int m    = lane & 15;
    int q    = lane >> 4;

    int ra0 = rt * 128 + w * 16 + m;        if (ra0 > M - 1) ra0 = M - 1;
    int ra1 = rt * 128 + (4 + w) * 16 + m;  if (ra1 > M - 1) ra1 = M - 1;
    int rb  = ct * 64 + w * 16 + m;
    const unsigned short* pa0 = Aext + (size_t)ra0 * 2 * K + q * 8;
    const unsigned short* pa1 = Aext + (size_t)ra1 * 2 * K + q * 8;
    const unsigned short* pb  = Bext + (size_t)rb  * 2 * K + q * 8;
    unsigned short* Bs = sh + 8192;

    f32x4 acc[4][2];
#pragma unroll
    for (int i = 0; i < 4; ++i)
#pragma unroll
        for (int j = 0; j < 2; ++j) acc[i][j] = (f32x4){0.f, 0.f, 0.f, 0.f};

    for (int k0 = 0; k0 < K; k0 += 32) {
        gld_lds16(pa0 + k0,     sh + (w * 2 + 0) * 512);
        gld_lds16(pa0 + K + k0, sh + (w * 2 + 1) * 512);
        gld_lds16(pa1 + k0,     sh + ((4 + w) * 2 + 0) * 512);
        gld_lds16(pa1 + K + k0, sh + ((4 + w) * 2 + 1) * 512);
        gld_lds16(pb + k0,      Bs + (w * 2 + 0) * 512);
        gld_lds16(pb + K + k0,  Bs + (w * 2 + 1) * 512);
        __syncthreads();
        short8 ah[4], al[4];
#pragma unroll
        for (int i = 0; i < 4; ++i) {
            ah[i] = *(const short8*)&sh[((wy * 4 + i) * 2 + 0) * 512 + lane * 8];
            al[i] = *(const short8*)&sh[((wy * 4 + i) * 2 + 1) * 512 + lane * 8];
        }
#pragma unroll
        for (int j = 0; j < 2; ++j) {
            short8 bh = *(const short8*)&Bs[((wx * 2 + j) * 2 + 0) * 512 + lane * 8];
            short8 bl = *(const short8*)&Bs[((wx * 2 + j) * 2 + 1) * 512 + lane * 8];
#pragma unroll
            for (int i = 0; i < 4; ++i) {
                acc[i][j] = __builtin_amdgcn_mfma_f32_16x16x32_bf16(ah[i], bh, acc[i][j], 0, 0, 0);
                acc[i][j] = __builtin_amdgcn_mfma_f32_16x16x32_bf16(al[i], bh, acc[i][j], 0, 0, 0);
                acc[i][j] = __builtin_amdgcn_mfma_f32_16x16x32_bf16(ah[i], bl, acc[i][j], 0, 0, 0);
            }
        }
        __syncthreads();
    }

    float b0 = 0.f, b1 = 0.f;
    if (bias) {
        b0 = bias[ct * 64 + wx * 32 + m];
        b1 = bias[ct * 64 + wx * 32 + 16 + m];
    }
#pragma unroll
    for (int i = 0; i < 4; ++i) {
        int rbase = rt * 128 + wy * 64 + i * 16 + q * 4;
#pragma unroll
        for (int j = 0; j < 2; ++j) {
            int col = ct * 64 + wx * 32 + j * 16 + m;
            float bb = j ? b1 : b0;
#pragma unroll
            for (int reg = 0; reg < 4; ++reg) {
                int row = rbase + reg;
                if (row < M) {
                    float v = acc[i][j][reg] + bb;
                    if (relu) v = fmaxf(v, 0.f);
                    if (ext == 0) {
                        ((float*)Cout)[(size_t)row * N + col] = v;
                    } else {
                        unsigned short hi = f2bf(v);
                        unsigned short lo = f2bf(v - bf2f(hi));
                        unsigned short* ob = (unsigned short*)Cout + (size_t)row * 2 * N;
                        ob[col] = hi; ob[N + col] = lo;
                    }
                }
            }
        }
    }
}

// dualA: GCN1 GEMM (ct 0..3, rt 0..78, M=10000, fp32 out) + MLP1 (ct 4..7,
// rt 0..31, M=4096, relu+ext out). Independent — share one launch.
__global__ __launch_bounds__(256, 4) void mfma_gemm_dualA_kernel(
        const unsigned short* __restrict__ A0, const unsigned short* __restrict__ B0,
        void* __restrict__ C0,
        const unsigned short* __restrict__ A1, const unsigned short* __restrict__ B1,
        const float* __restrict__ bias1, void* __restrict__ C1) {
    __shared__ __align__(16) unsigned short sh[12288];
    if ((int)blockIdx.x < 4) {
        gemm_body(A0, B0, nullptr, C0, N_NODES, HID, DIM, blockIdx.y, blockIdx.x, 0, 0, sh);
    } else {
        gemm_body(A1, B1, bias1, C1, BATCH, HID, DIM, blockIdx.y, blockIdx.x - 4, 1, 1, sh);
    }
}

// dualB: GCN2 GEMM (ct 0..7, M=pcnt, ext out; dead rt tiles early-exit) +
// MLP2 (ct 8..15, relu+ext out).
__global__ __launch_bounds__(256, 4) void mfma_gemm_dualB_kernel(
        const unsigned short* __restrict__ A0, const unsigned short* __restrict__ B0,
        const float* __restrict__ bias0, void* __restrict__ C0,
        const int* __restrict__ Mptr0,
        const unsigned short* __restrict__ A1, const unsigned short* __restrict__ B1,
        const float* __restrict__ bias1, void* __restrict__ C1) {
    __shared__ __align__(16) unsigned short sh[12288];
    if ((int)blockIdx.x < 8) {
        gemm_body(A0, B0, bias0, C0, Mptr0[0], DIM, HID, blockIdx.y, blockIdx.x, 0, 1, sh);
    } else {
        gemm_body(A1, B1, bias1, C1, BATCH, DIM, HID, blockIdx.y, blockIdx.x - 8, 1, 1, sh);
    }
}

// ---------------------------------------------------------------------------
// logits = A @ B^T on [hi|lo] ext (K=512, 3-product split-bf16) + fused online
// softmax partials. 256x128 tile, 512 thr = 8 waves (4x2), wave = 64x64.
// 48 KB LDS -> 2 blocks/CU; 512 blocks full residency. In-kernel A-gather via
// pos[label]; fragment-order LDS (conflict-free); XCD swizzle.
// ---------------------------------------------------------------------------
__global__ __launch_bounds__(512, 4) void logits_mfma_kernel(
        const unsigned short* __restrict__ Aext, const unsigned short* __restrict__ Bext,
        const int* __restrict__ label, const int* __restrict__ pos,
        float* __restrict__ pmax, float* __restrict__ psum, float* __restrict__ diagv) {
    __shared__ __align__(16) unsigned short sh[24576];   // 48 KB: A 32KB (16 chunks) + B 16KB (8)
    unsigned short* Bs = sh + 16384;

    int t    = threadIdx.x;
    int lane = t & 63;
    int w    = t >> 6;            // wave 0..7
    int wy   = w >> 1, wx = w & 1;
    // XCD swizzle over 512 blocks = 16 rt x 32 ct; per-XCD region 8rt x 8ct
    int g   = blockIdx.x;
    int xcd = g & 7, s = g >> 3;              // s in 0..63
    int rt  = (xcd & 1) * 8 + (s & 7);        // 0..15 (256-row tiles)
    int ct  = (xcd >> 1) * 8 + (s >> 3);      // 0..31 (128-col tiles)
    int m    = lane & 15;
    int q    = lane >> 4;

    // staging: wave w owns A chunks (w*2, w*2+1) and B chunk w (16 rows each)
    int ar0 = pos[label[rt * 256 + (w * 2 + 0) * 16 + m]];
    int ar1 = pos[label[rt * 256 + (w * 2 + 1) * 16 + m]];
    const unsigned short* ap0 = Aext + (size_t)ar0 * 1024 + q * 8;
    const unsigned short* ap1 = Aext + (size_t)ar1 * 1024 + q * 8;
    const unsigned short* bp  = Bext + (size_t)(ct * 128 + w * 16 + m) * 1024 + q * 8;

    f32x4 acc[4][4];
#pragma unroll
    for (int i = 0; i < 4; ++i)
#pragma unroll
        for (int j = 0; j < 4; ++j) acc[i][j] = (f32x4){0.f, 0.f, 0.f, 0.f};

    for (int k0 = 0; k0 < 512; k0 += 32) {
        gld_lds16(ap0 + k0,       sh + ((w * 2 + 0) * 2 + 0) * 512);
        gld_lds16(ap0 + 512 + k0, sh + ((w * 2 + 0) * 2 + 1) * 512);
        gld_lds16(ap1 + k0,       sh + ((w * 2 + 1) * 2 + 0) * 512);
        gld_lds16(ap1 + 512 + k0, sh + ((w * 2 + 1) * 2 + 1) * 512);
        gld_lds16(bp + k0,        Bs + (w * 2 + 0) * 512);
        gld_lds16(bp + 512 + k0,  Bs + (w * 2 + 1) * 512);
        __syncthreads();                 // drains vmcnt: staging complete
        short8 ah[4], al[4];
#pragma unroll
        for (int i = 0; i < 4; ++i) {
            ah[i] = *(const short8*)&sh[((wy * 4 + i) * 2 + 0) * 512 + lane * 8];
            al[i] = *(const short8*)&sh[((wy * 4 + i) * 2 + 1) * 512 + lane * 8];
        }
#pragma unroll
        for (int j = 0; j < 4; ++j) {
            short8 bh = *(const short8*)&Bs[((wx * 4 + j) * 2 + 0) * 512 + lane * 8];
            short8 bl = *(const short8*)&Bs[((wx * 4 + j) * 2 + 1) * 512 + lane * 8];
#pragma unroll
            for (int i = 0; i < 4; ++i) {
                acc[i][j] = __builtin_amdgcn_mfma_f32_16x16x32_bf16(ah[i], bh, acc[i][j], 0, 0, 0);
                acc[i][j] = __builtin_amdgcn_mfma_f32_16x16x32_bf16(al[i], bh, acc[i][j], 0, 0, 0);
                acc[i][j] = __builtin_amdgcn_mfma_f32_16x16x32_bf16(ah[i], bl, acc[i][j], 0, 0, 0);
            }
        }
        __syncthreads();                 // WAR before next staging
    }

    // C/D layout: col = lane&15, row = q*4 + reg (within each 16x16 tile)
    // diagonal: block touches it iff ct>>1 == rt
    if ((ct >> 1) == rt) {
#pragma unroll
        for (int i = 0; i < 4; ++i)
#pragma unroll
            for (int j = 0; j < 4; ++j)
#pragma unroll
                for (int reg = 0; reg < 4; ++reg) {
                    int row = rt * 256 + wy * 64 + i * 16 + q * 4 + reg;
                    int col = ct * 128 + wx * 64 + j * 16 + m;
                    if (row == col) diagv[row] = acc[i][j][reg];
                }
    }

    // per-row (max, sumexp) over this wave's 64 cols
#pragma unroll
    for (int mt = 0; mt < 4; ++mt) {
#pragma unroll
        for (int reg = 0; reg < 4; ++reg) {
            float v0 = acc[mt][0][reg], v1 = acc[mt][1][reg];
            float v2 = acc[mt][2][reg], v3 = acc[mt][3][reg];
            float mx = fmaxf(fmaxf(v0, v1), fmaxf(v2, v3));
#pragma unroll
            for (int d = 1; d < 16; d <<= 1) mx = fmaxf(mx, __shfl_xor(mx, d, 64));
            float sm = __expf(v0 - mx) + __expf(v1 - mx) + __expf(v2 - mx) + __expf(v3 - mx);
#pragma unroll
            for (int d = 1; d < 16; d <<= 1) sm += __shfl_xor(sm, d, 64);
            if (m == 0) {
                int row = rt * 256 + wy * 64 + mt * 16 + q * 4 + reg;
                pmax[(size_t)row * 64 + ct * 2 + wx] = mx;
                psum[(size_t)row * 64 + ct * 2 + wx] = sm;
            }
        }
    }
}

// combine 64 col-tile partials per row -> per-row loss term; fused final
// reduction via device-scope atomics (last block writes out[0]).
__global__ __launch_bounds__(256) void row_finalize_kernel(const float* __restrict__ pmax,
        const float* __restrict__ psum, const float* __restrict__ diagv,
        const int* __restrict__ label, float* __restrict__ facc, int* __restrict__ fcnt,
        float* __restrict__ out) {
    __shared__ float wsum[4];
    int gid  = blockIdx.x * blockDim.x + threadIdx.x;
    int row  = gid >> 6;
    int lane = threadIdx.x & 63;
    int wv   = threadIdx.x >> 6;
    float term = 0.0f;
    if (row < BATCH) {
        float m = pmax[(size_t)row * 64 + lane];
        float s = psum[(size_t)row * 64 + lane];
        float M = m;
#pragma unroll
        for (int d = 1; d < 64; d <<= 1) M = fmaxf(M, __shfl_xor(M, d, 64));
        s *= __expf(m - M);
#pragma unroll
        for (int d = 1; d < 64; d <<= 1) s += __shfl_xor(s, d, 64);
        float lse = M + __logf(s);
        term = -(float)label[row] * (diagv[row] - lse);
    }
    if (lane == 0) wsum[wv] = (row < BATCH) ? term : 0.0f;
    __syncthreads();
    if (threadIdx.x == 0) {
        float p = wsum[0] + wsum[1] + wsum[2] + wsum[3];
        atomicAdd(facc, p);
        __threadfence();
        int old = atomicAdd(fcnt, 1);
        if (old == (int)gridDim.x - 1) {
            float tot = atomicAdd(facc, 0.0f);   // device-scope coherent read
            // contrastive mean + triplet loss (identically 1.0: d_ap==d_an)
            out[0] = tot / (float)BATCH + 1.0f;
        }
    }
}

// ---------------------------------------------------------------------------
extern "C" void kernel_launch(void* const* d_in, const int* in_sizes, int n_in,
                              void* d_out, int out_size, void* d_ws, size_t ws_size,
                              hipStream_t stream) {
    const float* image   = (const float*)d_in[0];
    const float* x_nodes = (const float*)d_in[1];
    const int*   edge    = (const int*)d_in[2];
    const int*   label   = (const int*)d_in[3];
    const float* W_img1  = (const float*)d_in[4];
    const float* b_img1  = (const float*)d_in[5];
    const float* W_img2  = (const float*)d_in[6];
    const float* b_img2  = (const float*)d_in[7];
    const float* W_g1    = (const float*)d_in[8];
    const float* b_g1    = (const float*)d_in[9];
    const float* W_g2    = (const float*)d_in[10];
    const float* b_g2    = (const float*)d_in[11];
    const int* src = edge;              // edge_index[0]
    const int* dst = edge + N_EDGES;    // edge_index[1]

    // workspace carve-up (256B aligned regions)
    char* ws = (char*)d_ws;
    size_t off = 0;
    auto alloc = [&](size_t bytes) { size_t r = off; off = (off + bytes + 255) & ~(size_t)255; return r; };
    float* dinv     = (float*)(ws + alloc(N_NODES * 4));
    int*   cnt      = (int*)  (ws + alloc(N_NODES * 4));
    int*   offs     = (int*)  (ws + alloc((N_NODES + 1) * 4));
    int*   cursor   = (int*)  (ws + alloc(N_NODES * 4));
    int*   csr_src  = (int*)  (ws + alloc(N_EDGES * 4));
    float* csr_w    = (float*)(ws + alloc(N_EDGES * 4));
    int*   flag     = (int*)  (ws + alloc(N_NODES * 4));
    int*   pos      = (int*)  (ws + alloc(N_NODES * 4));
    int*   nodelist = (int*)  (ws + alloc(BATCH * 4));
    int*   pcnt     = (int*)  (ws + alloc(4));
    int*   bsum     = (int*)  (ws + alloc(64 * 4));
    float* facc     = (float*)(ws + alloc(4));
    int*   fcnt     = (int*)  (ws + alloc(4));
    float* xw1      = (float*)(ws + alloc((size_t)N_NODES * HID * 4));
    float* h        = (float*)(ws + alloc((size_t)N_NODES * HID * 4));
    unsigned short* g2inext = (unsigned short*)(ws + alloc((size_t)BATCH * 2 * HID * 2));
    unsigned short* g2ext   = (unsigned short*)(ws + alloc((size_t)BATCH * 2 * DIM * 2));
    unsigned short* himgext = (unsigned short*)(ws + alloc((size_t)BATCH * 2 * HID * 2));
    unsigned short* extbuf  = (unsigned short*)(ws + alloc((size_t)N_NODES * 2 * DIM * 2));
    unsigned short* imgext  = (unsigned short*)(ws + alloc((size_t)BATCH * 2 * DIM * 2));
    unsigned short* wext1   = (unsigned short*)(ws + alloc((size_t)HID * 2 * DIM * 2));
    unsigned short* wext2   = (unsigned short*)(ws + alloc((size_t)DIM * 2 * HID * 2));
    unsigned short* wext3   = (unsigned short*)(ws + alloc((size_t)HID * 2 * DIM * 2));
    unsigned short* wext4   = (unsigned short*)(ws + alloc((size_t)DIM * 2 * HID * 2));
    unsigned short* Bext    = (unsigned short*)(ws + alloc((size_t)BATCH * 2 * DIM * 2));
    float* pmax  = (float*)(ws + alloc((size_t)BATCH * 64 * 4));
    float* psum  = (float*)(ws + alloc((size_t)BATCH * 64 * 4));
    float* diagv = (float*)(ws + alloc(BATCH * 4));

    const int SCAN_BLOCKS = (N_NODES + 255) / 256;   // 40

    // graph build: CSR by dst (storing src+weight) + dinv + label compaction
    zero_init_kernel<<<SCAN_BLOCKS, 256, 0, stream>>>(cnt, cursor, flag, pcnt, facc, fcnt);
    count_mark_kernel<<<(N_EDGES + 255) / 256, 256, 0, stream>>>(dst, label, cnt, flag);
    scanA_kernel<<<SCAN_BLOCKS, 256, 0, stream>>>(cnt, offs, bsum, dinv);
    scanC_kernel<<<SCAN_BLOCKS, 256, 0, stream>>>(offs, bsum);
    fill_compact_kernel<<<(N_EDGES + 255) / 256, 256, 0, stream>>>(
        src, dst, offs, dinv, cursor, csr_src, csr_w, flag, pcnt, nodelist, pos);

    // all operand builds (x_nodes + image row-ext, 4 weight col-ext) in one launch
    build_all_kernel<<<((N_NODES + BATCH) * 128 + 4 * 32768) / 256, 256, 0, stream>>>(
        x_nodes, image, W_g1, W_img1, W_g2, W_img2,
        extbuf, imgext, wext1, wext3, wext2, wext4);

    // dualA: GCN1 GEMM (xw1 = x_nodes @ W_g1) + MLP1 (himgext) — independent
    mfma_gemm_dualA_kernel<<<dim3(8, (N_NODES + 127) / 128), 256, 0, stream>>>(
        extbuf, wext1, xw1, imgext, wext3, b_img1, himgext);

    // GCN layer 1 aggregation: h = relu(A-hat xw1 + b1)  (no-LDS kernel, max occupancy)
    agg256_kernel<1, 1, 0, 0><<<(N_NODES + 3) / 4, 256, 0, stream>>>(
        xw1, dinv, csr_src, csr_w, offs, b_g1, h, nullptr, nullptr);

    // GCN layer 2 aggregation (compact label rows)
    agg256_kernel<0, 0, 1, 1><<<BATCH / 4, 256, 0, stream>>>(
        h, dinv, csr_src, csr_w, offs, nullptr, g2inext, nodelist, pcnt);

    // dualB: GCN2 GEMM (g2ext, M=pcnt) + MLP2 (Bext) — independent at this point
    mfma_gemm_dualB_kernel<<<dim3(16, BATCH / 128), 256, 0, stream>>>(
        g2inext, wext2, b_g2, g2ext, pcnt, himgext, wext4, b_img2, Bext);

    // fused logits (split-bf16 MFMA, 256x128 tile) + online softmax partials
    logits_mfma_kernel<<<512, 512, 0, stream>>>(g2ext, Bext, label, pos,
                                                pmax, psum, diagv);
    // per-row LSE + fused mean + triplet constant
    row_finalize_kernel<<<(BATCH * 64) / 256, 256, 0, stream>>>(
        pmax, psum, diagv, label, facc, fcnt, (float*)d_out);
}